// Round 20
// baseline (199.595 us; speedup 1.0000x reference)
//
#include <hip/hip_runtime.h>

namespace {

constexpr int DIMC  = 1024;
constexpr int HEADS = 16;
constexpr int HD    = 64;
constexpr int BATCH = 4;
constexpr int SEQ   = 2048;
constexpr float SC2 = 0.18033688011112042f;   // (1/sqrt(64)) * log2(e)

typedef __attribute__((ext_vector_type(8))) short short8;   // 8 bf16 (4 VGPRs)
typedef __attribute__((ext_vector_type(4))) float f32x4;

__device__ __forceinline__ unsigned short f2bf(float f) {
    union { float f; unsigned u; } v; v.f = f;
    unsigned r = v.u + 0x7fffu + ((v.u >> 16) & 1u);   // RNE
    return (unsigned short)(r >> 16);
}

// native exp2: v_exp_f32 computes D=2^S0 in ONE instruction (~1 ULP).
__device__ __forceinline__ float fexp2(float x) {
    float r;
    asm("v_exp_f32 %0, %1" : "=v"(r) : "v"(x));
    return r;
}

// async global->LDS, 16B per lane; ldst must be wave-uniform base (HW adds lane*16)
__device__ __forceinline__ void gl16(const unsigned short* gsrc, const unsigned short* ldst) {
    __builtin_amdgcn_global_load_lds(
        (const __attribute__((address_space(1))) void*)gsrc,
        (__attribute__((address_space(3))) void*)ldst, 16, 0, 0);
}

// ---------------------------------------------------------------------------
// fused fp32 -> bf16 conversion of x, qkv_w, out_w (one launch)
// ---------------------------------------------------------------------------
__global__ __launch_bounds__(256) void cvt3_f32_bf16(
    const float* __restrict__ x,  const float* __restrict__ wq,
    const float* __restrict__ wo,
    unsigned short* __restrict__ xb, unsigned short* __restrict__ wqb,
    unsigned short* __restrict__ wob)
{
    constexpr int N0 = 8192*1024/8;       // x
    constexpr int N1 = 3072*1024/8;       // qkv_w
    constexpr int N2 = 1024*1024/8;       // out_w
    for (int i = blockIdx.x * blockDim.x + threadIdx.x; i < N0 + N1 + N2;
         i += gridDim.x * blockDim.x) {
        const float* src; unsigned short* dst; int j;
        if (i < N0)           { src = x;  dst = xb;  j = i; }
        else if (i < N0 + N1) { src = wq; dst = wqb; j = i - N0; }
        else                  { src = wo; dst = wob; j = i - N0 - N1; }
        const float4 a = ((const float4*)src)[2*j];
        const float4 b = ((const float4*)src)[2*j + 1];
        union { unsigned short s[8]; uint4 u; } p;
        p.s[0]=f2bf(a.x); p.s[1]=f2bf(a.y); p.s[2]=f2bf(a.z); p.s[3]=f2bf(a.w);
        p.s[4]=f2bf(b.x); p.s[5]=f2bf(b.y); p.s[6]=f2bf(b.z); p.s[7]=f2bf(b.w);
        ((uint4*)dst)[j] = p.u;
    }
}

// ---------------------------------------------------------------------------
// bf16 GEMM: C[M,N] = A[M,K] @ W[N,K]^T + bias.  128x128 tile, BK=32,
// 4 waves (2x2), 64x64/wave. Double-buffered global_load_lds prefetch;
// XOR-swizzled LDS; XCD-aware 1D grid (nwg%8==0, bijective).
// OUT_MODE: 0 = f32 output.  2 = QKV mode: bf16 output for cols<2048,
// cols>=2048 (the V third) written TRANSPOSED into vt[(b*16+h)*64+d][s].
// ---------------------------------------------------------------------------
template<int OUT_MODE>
__global__ __launch_bounds__(256) void gemm_bf16_mfma(
    const unsigned short* __restrict__ A, const unsigned short* __restrict__ W,
    const float* __restrict__ bias, void* __restrict__ Cout,
    unsigned short* __restrict__ vt,
    int M, int N, int K, int nbx)
{
    __shared__ __align__(16) char lds[32768];   // A0 B0 A1 B1 (8KB each)
    unsigned short* base = (unsigned short*)lds;

    const int tid = threadIdx.x;
    const int w = tid >> 6, l = tid & 63;
    const int wr = w >> 1, wc = w & 1;
    const int fr = l & 15, fq = l >> 4;

    // XCD-aware decode: consecutive nid on one XCD share the A row-panel
    const int qx  = gridDim.x >> 3;
    const int nid = (blockIdx.x & 7) * qx + (blockIdx.x >> 3);
    const int bx  = nid % nbx, by = nid / nbx;
    const int row0 = by * 128, col0 = bx * 128;

    const int sr0 = (w*2 + 0)*16 + (l >> 2);
    const int sr1 = (w*2 + 1)*16 + (l >> 2);
    const int skz = (((l & 3) ^ ((l >> 3) & 3))) * 8;   // swizzled source col

    const unsigned short* Ab0 = A + (size_t)(row0 + sr0)*K + skz;
    const unsigned short* Ab1 = A + (size_t)(row0 + sr1)*K + skz;
    const unsigned short* Wb0 = W + (size_t)(col0 + sr0)*K + skz;
    const unsigned short* Wb1 = W + (size_t)(col0 + sr1)*K + skz;

    f32x4 acc[4][4];
#pragma unroll
    for (int mi = 0; mi < 4; ++mi)
#pragma unroll
        for (int ni = 0; ni < 4; ++ni)
#pragma unroll
            for (int r = 0; r < 4; ++r) acc[mi][ni][r] = 0.f;

    const int cfa = (fq ^ ((fr >> 1) & 3)) * 8;

    auto stage = [&](int k0, int buf) {
        unsigned short* Ad = base + buf*8192;
        unsigned short* Wd = Ad + 4096;
        gl16(Ab0 + k0, Ad + (w*2 + 0)*512);
        gl16(Ab1 + k0, Ad + (w*2 + 1)*512);
        gl16(Wb0 + k0, Wd + (w*2 + 0)*512);
        gl16(Wb1 + k0, Wd + (w*2 + 1)*512);
    };

    stage(0, 0);
    for (int k0 = 0; k0 < K; k0 += 32) {
        const int buf = (k0 >> 5) & 1;
        __syncthreads();                    // tile(k0) ready
        if (k0 + 32 < K) stage(k0 + 32, buf ^ 1);

        const unsigned short* Ac = base + buf*8192;
        const unsigned short* Wc = Ac + 4096;
        short8 af[4], bf[4];
#pragma unroll
        for (int mi = 0; mi < 4; ++mi)
            af[mi] = *(const short8*)(Ac + (wr*64 + mi*16 + fr)*32 + cfa);
#pragma unroll
        for (int ni = 0; ni < 4; ++ni)
            bf[ni] = *(const short8*)(Wc + (wc*64 + ni*16 + fr)*32 + cfa);
#pragma unroll
        for (int mi = 0; mi < 4; ++mi)
#pragma unroll
            for (int ni = 0; ni < 4; ++ni)
                acc[mi][ni] = __builtin_amdgcn_mfma_f32_16x16x32_bf16(
                    af[mi], bf[ni], acc[mi][ni], 0, 0, 0);
    }

    float bv[4];
#pragma unroll
    for (int ni = 0; ni < 4; ++ni) bv[ni] = bias[col0 + wc*64 + ni*16 + fr];
#pragma unroll
    for (int mi = 0; mi < 4; ++mi)
#pragma unroll
        for (int ni = 0; ni < 4; ++ni)
#pragma unroll
            for (int r = 0; r < 4; ++r) acc[mi][ni][r] += bv[ni];

    __syncthreads();                           // tiles dead; reuse LDS for repack
    float* rp = (float*)lds + w*1088;          // per-wave [16][68] f32
    const int orow = l >> 2, oc = (l & 3) * 16;
    const bool vmode = (OUT_MODE == 2) && (col0 >= 2048);
    const int hh = vmode ? ((col0 + wc*64 - 2048) >> 6) : 0;

#pragma unroll
    for (int mi = 0; mi < 4; ++mi) {
#pragma unroll
        for (int ni = 0; ni < 4; ++ni)
#pragma unroll
            for (int r = 0; r < 4; ++r)
                rp[(fq*4 + r)*68 + ni*16 + fr] = acc[mi][ni][r];
        // wave-lockstep: compiler orders LDS write->read within the wave
        if (vmode) {
            // TRANSPOSED V write: lane l = head-dim column d; 16 s-values -> 32B
            float cv[16];
#pragma unroll
            for (int j = 0; j < 16; ++j) cv[j] = rp[j*68 + l];
            union { unsigned short s[16]; uint4 u[2]; } pk;
#pragma unroll
            for (int j = 0; j < 16; ++j) pk.s[j] = f2bf(cv[j]);
            const int srow0 = row0 + wr*64 + mi*16;
            const int bb = srow0 >> 11, ss = srow0 & 2047;
            unsigned short* dst = vt + ((size_t)((bb*16 + hh)*64 + l))*SEQ + ss;
            ((uint4*)dst)[0] = pk.u[0];
            ((uint4*)dst)[1] = pk.u[1];
        } else {
            float vrow[16];
#pragma unroll
            for (int j = 0; j < 4; ++j)
                *(f32x4*)&vrow[j*4] = *(const f32x4*)&rp[orow*68 + oc + j*4];
            const size_t grow = (size_t)(row0 + wr*64 + mi*16 + orow);
            const int    gcol = col0 + wc*64 + oc;
            if (OUT_MODE == 2) {
                union { unsigned short s[16]; uint4 u[2]; } pk;
#pragma unroll
                for (int j = 0; j < 16; ++j) pk.s[j] = f2bf(vrow[j]);
                uint4* dst = (uint4*)((unsigned short*)Cout + grow*N + gcol);
                dst[0] = pk.u[0]; dst[1] = pk.u[1];
            } else {
                float* dst = (float*)Cout + grow*N + gcol;
#pragma unroll
                for (int j = 0; j < 4; ++j)
                    *(f32x4*)(dst + j*4) = *(const f32x4*)&vrow[j*4];
            }
        }
    }
}

// ---------------------------------------------------------------------------
// MFMA flash attention. 4 waves / 256 threads, QBLK=128 (32 q-rows/wave),
// KVBLK=32, pool 34816 B -> 4 blocks/CU (grid 1024) = 16 waves/CU.
// STATIC softmax: S^T = mfma(K, Q*SC2); P = v_exp_f32(S); l = mfma(ones,P);
// O^T = mfma(V^T, P^T).  K/V LDS dbuf via gl16 with pre-swizzled sources:
//   K tile [32 kv][64 d] (128B rows): LDS[r][c] = src[r][c ^ (r&7)]
//   V tile [64 d][32 kv] (64B rows):  LDS[r][c] = src[r][c ^ ((r>>1)&3)]
//   P per wave [32 q][40 hw pad] (80B rows, 16B-aligned, 2-way banks)
// ---------------------------------------------------------------------------
__global__ __launch_bounds__(256) void attn_mfma(
    const unsigned short* __restrict__ qkvb,
    const unsigned short* __restrict__ vt,
    unsigned short* __restrict__ ctxb)
{
    __shared__ __align__(16) char pool[34816];
    unsigned short* hw = (unsigned short*)pool;
    // halfword offsets: K buf@ buf*2048 (4KB each); V @4096 + buf*2048;
    // P @8192 + w*1280 ([32][40] per wave). Epilogue overlay uses full pool.

    const int tid = threadIdx.x, w = tid >> 6, l = tid & 63;
    const int fr = l & 15, fq = l >> 4;

    // XCD-aware decode (1024 blocks, 8 XCDs, bijective since 1024%8==0)
    const int bid = blockIdx.x;
    const int nid = (bid & 7) * 128 + (bid >> 3);
    const int b  = nid >> 8;
    const int h  = (nid >> 4) & 15;
    const int q0 = (nid & 15) * 128;
    const int wq = q0 + w*32;                      // 32 q-rows per wave

    const unsigned short* qb = qkvb + (size_t)b*SEQ*3072 + h*64;
    const unsigned short* kb = qb + 1024;
    const unsigned short* vb = vt + (size_t)((b*16 + h)*64)*SEQ;

    // Q fragments, scaled by SC2 once (bf16 relative precision unchanged)
    auto scale8 = [](short8 v) -> short8 {
        union { short8 s; unsigned u[4]; } in, out;
        in.s = v;
#pragma unroll
        for (int i = 0; i < 4; ++i) {
            const float lo = __uint_as_float(in.u[i] << 16) * SC2;
            const float hi = __uint_as_float(in.u[i] & 0xffff0000u) * SC2;
            unsigned r;
            asm("v_cvt_pk_bf16_f32 %0, %1, %2" : "=v"(r) : "v"(lo), "v"(hi));
            out.u[i] = r;
        }
        return out.s;
    };
    short8 qf[2][2];
#pragma unroll
    for (int mf = 0; mf < 2; ++mf)
#pragma unroll
        for (int kk = 0; kk < 2; ++kk)
            qf[mf][kk] = scale8(*(const short8*)(qb + (size_t)(wq + mf*16 + fr)*3072
                                                 + kk*32 + fq*8));

    short8 ones;
#pragma unroll
    for (int i = 0; i < 8; ++i) ones[i] = (short)0x3F80;   // bf16 1.0

    f32x4 z4;
#pragma unroll
    for (int r = 0; r < 4; ++r) z4[r] = 0.f;

    f32x4 o[2][4];     // o[mf][df][r]: q=mf*16+fr, d=df*16+fq*4+r
    f32x4 ol[2];       // l accumulators
#pragma unroll
    for (int mf = 0; mf < 2; ++mf) {
#pragma unroll
        for (int df = 0; df < 4; ++df)
#pragma unroll
            for (int r = 0; r < 4; ++r) o[mf][df][r] = 0.f;
#pragma unroll
        for (int r = 0; r < 4; ++r) ol[mf][r] = 0.f;
    }

    // K staging: wave w covers rows w*8..w*8+7; lane row w*8+(l>>3), chunk l&7
    const int srK  = w*8 + (l >> 3);
    const int sczK = ((l & 7) ^ (l >> 3)) * 8;
    // V staging: wave w covers rows w*16..+15; lane row w*16+(l>>2), chunk l&3
    const int srV  = w*16 + (l >> 2);
    const int sczV = ((l & 3) ^ ((w*8 + (l >> 3)) & 3)) * 8;   // (row>>1)&3 swizzle

    unsigned short* Pw = hw + 8192 + w*1280;       // [32][40]

    const int cK0 = (fq ^ (fr & 7)) * 8;           // K frag chunk (d 0..31)
    const int cK1 = cK0 ^ 32;                      // d 32..63
    const int cV  = (fq ^ ((fr >> 1) & 3)) * 8;    // V frag chunk

    auto stage = [&](int kv0, int buf) {
        gl16(kb + (size_t)(kv0 + srK)*3072 + sczK, hw + buf*2048 + w*512);
        gl16(vb + (size_t)srV*SEQ + kv0 + sczV,    hw + 4096 + buf*2048 + w*512);
    };

    stage(0, 0);
    for (int kv0 = 0; kv0 < SEQ; kv0 += 32) {
        const int buf = (kv0 >> 5) & 1;
        __syncthreads();                 // tile(kv0) DMA done; buf^1 free
        if (kv0 + 32 < SEQ) stage(kv0 + 32, buf ^ 1);

        const unsigned short* Kc = hw + buf*2048;
        const unsigned short* Vc = hw + 4096 + buf*2048;

        // V fragments EARLY (latency overlaps S + exp)
        short8 vf[4];
#pragma unroll
        for (int df = 0; df < 4; ++df)
            vf[df] = *(const short8*)(Vc + (df*16 + fr)*32 + cV);

        // ---- S^T = K (Q*SC2)^T : s[mf][nf][r] = S^T[kv=nf*16+fq*4+r][q=mf*16+fr]
        f32x4 s[2][2];
#pragma unroll
        for (int nf = 0; nf < 2; ++nf) {
            const short8 k0f = *(const short8*)(Kc + (nf*16 + fr)*64 + cK0);
            const short8 k1f = *(const short8*)(Kc + (nf*16 + fr)*64 + cK1);
#pragma unroll
            for (int mf = 0; mf < 2; ++mf) {
                s[mf][nf] = __builtin_amdgcn_mfma_f32_16x16x32_bf16(k0f, qf[mf][0], z4, 0,0,0);
                s[mf][nf] = __builtin_amdgcn_mfma_f32_16x16x32_bf16(k1f, qf[mf][1], s[mf][nf], 0,0,0);
            }
        }

        // ---- P = exp2(s), pack bf16, uint2 store into P[32][40] ----
#pragma unroll
        for (int mf = 0; mf < 2; ++mf)
#pragma unroll
            for (int nf = 0; nf < 2; ++nf) {
                const float p0 = fexp2(s[mf][nf][0]);
                const float p1 = fexp2(s[mf][nf][1]);
                const float p2 = fexp2(s[mf][nf][2]);
                const float p3 = fexp2(s[mf][nf][3]);
                unsigned u0, u1;
                asm("v_cvt_pk_bf16_f32 %0, %1, %2" : "=v"(u0) : "v"(p0), "v"(p1));
                asm("v_cvt_pk_bf16_f32 %0, %1, %2" : "=v"(u1) : "v"(p2), "v"(p3));
                uint2 pw; pw.x = u0; pw.y = u1;
                *(uint2*)(Pw + (mf*16 + fr)*40 + nf*16 + fq*4) = pw;
            }

        // ---- O^T += V^T P^T ; l += ones . P^T  (kv=32: one mfma each) ----
        short8 pa[2];
#pragma unroll
        for (int mf = 0; mf < 2; ++mf)
            pa[mf] = *(const short8*)(Pw + (mf*16 + fr)*40 + fq*8);
#pragma unroll
        for (int mf = 0; mf < 2; ++mf)
            ol[mf] = __builtin_amdgcn_mfma_f32_16x16x32_bf16(ones, pa[mf], ol[mf], 0,0,0);
#pragma unroll
        for (int df = 0; df < 4; ++df)
#pragma unroll
            for (int mf = 0; mf < 2; ++mf)
                o[mf][df] = __builtin_amdgcn_mfma_f32_16x16x32_bf16(
                    vf[df], pa[mf], o[mf][df], 0,0,0);
    }

    // ---- normalize + coalesced store via per-wave LDS repack ----
    __syncthreads();
    float* rp = (float*)(pool + w*8704);   // [32][68] f32, wave-private
    const float inv0 = 1.f / ol[0][0], inv1 = 1.f / ol[1][0];
#pragma unroll
    for (int df = 0; df < 4; ++df) {
        f32x4 v0 = o[0][df] * inv0;
        f32x4 v1 = o[1][df] * inv1;
        *(f32x4*)&rp[(fr)*68      + df*16 + fq*4] = v0;
        *(f32x4*)&rp[(16 + fr)*68 + df*16 + fq*4] = v1;
    }
    const int orow = l >> 1, oc = (l & 1)*32;
    float vr[32];
#pragma unroll
    for (int j = 0; j < 8; ++j)
        *(f32x4*)&vr[j*4] = *(const f32x4*)&rp[orow*68 + oc + j*4];
    union { unsigned short s[32]; uint4 u[4]; } pk;
#pragma unroll
    for (int j = 0; j < 32; ++j) pk.s[j] = f2bf(vr[j]);
    unsigned short* dst = ctxb + (size_t)(b*SEQ + q0 + w*32 + orow)*DIMC + h*64 + oc;
#pragma unroll
    for (int j = 0; j < 4; ++j) *((uint4*)dst + j) = pk.u[j];
}

} // namespace

extern "C" void kernel_launch(void* const* d_in, const int* in_sizes, int n_in,
                              void* d_out, int out_size, void* d_ws, size_t ws_size,
                              hipStream_t stream)
{
    const float* x     = (const float*)d_in[0];
    const float* qkv_w = (const float*)d_in[1];
    const float* qkv_b = (const float*)d_in[2];
    const float* out_w = (const float*)d_in[3];
    const float* out_b = (const float*)d_in[4];

    // workspace carve (bf16 buffers), ~109 MB total
    unsigned short* xb   = (unsigned short*)d_ws;              // [8192][1024]
    unsigned short* wqb  = xb   + (size_t)8192*1024;           // [3072][1024]
    unsigned short* wob  = wqb  + (size_t)3072*1024;           // [1024][1024]
    unsigned short* qkvb = wob  + (size_t)1024*1024;           // [8192][3072] (V third unused)
    unsigned short* vtw  = qkvb + (size_t)8192*3072;           // [4096][2048]
    unsigned short* ctxb = vtw  + (size_t)4096*2048;           // [8192][1024]

    // 1) fused fp32 -> bf16 conversions (one launch)
    cvt3_f32_bf16<<<2048, 256, 0, stream>>>(x, qkv_w, out_w, xb, wqb, wob);

    // 2) QKV projection (bf16 out; V third written transposed into vtw)
    gemm_bf16_mfma<2><<<dim3(1536), 256, 0, stream>>>(
        xb, wqb, qkv_b, (void*)qkvb, vtw, 8192, 3072, 1024, 24);

    // 3) flash attention (QBLK=128, KVBLK=32, 4 blocks/CU) -> ctx bf16
    attn_mfma<<<dim3(1024), 256, 0, stream>>>(qkvb, vtw, ctxb);

    // 4) output projection (f32 out): [8192,1024]x[1024,1024]^T + bias
    gemm_bf16_mfma<0><<<dim3(512), 256, 0, stream>>>(
        ctxb, wob, out_b, d_out, nullptr, 8192, 1024, 1024, 8);
}

// Round 21
// 196.157 us; speedup vs baseline: 1.0175x; 1.0175x over previous
//
#include <hip/hip_runtime.h>

namespace {

constexpr int DIMC  = 1024;
constexpr int HEADS = 16;
constexpr int HD    = 64;
constexpr int BATCH = 4;
constexpr int SEQ   = 2048;
constexpr float SC2 = 0.18033688011112042f;   // (1/sqrt(64)) * log2(e)

typedef __attribute__((ext_vector_type(8))) short short8;   // 8 bf16 (4 VGPRs)
typedef __attribute__((ext_vector_type(4))) float f32x4;

__device__ __forceinline__ unsigned short f2bf(float f) {
    union { float f; unsigned u; } v; v.f = f;
    unsigned r = v.u + 0x7fffu + ((v.u >> 16) & 1u);   // RNE
    return (unsigned short)(r >> 16);
}

// native exp2: v_exp_f32 computes D=2^S0 in ONE instruction (~1 ULP).
__device__ __forceinline__ float fexp2(float x) {
    float r;
    asm("v_exp_f32 %0, %1" : "=v"(r) : "v"(x));
    return r;
}

// async global->LDS, 16B per lane; ldst must be wave-uniform base (HW adds lane*16)
__device__ __forceinline__ void gl16(const unsigned short* gsrc, const unsigned short* ldst) {
    __builtin_amdgcn_global_load_lds(
        (const __attribute__((address_space(1))) void*)gsrc,
        (__attribute__((address_space(3))) void*)ldst, 16, 0, 0);
}

// ---------------------------------------------------------------------------
// fused fp32 -> bf16 conversion of x, qkv_w, out_w (one launch)
// ---------------------------------------------------------------------------
__global__ __launch_bounds__(256) void cvt3_f32_bf16(
    const float* __restrict__ x,  const float* __restrict__ wq,
    const float* __restrict__ wo,
    unsigned short* __restrict__ xb, unsigned short* __restrict__ wqb,
    unsigned short* __restrict__ wob)
{
    constexpr int N0 = 8192*1024/8;       // x
    constexpr int N1 = 3072*1024/8;       // qkv_w
    constexpr int N2 = 1024*1024/8;       // out_w
    for (int i = blockIdx.x * blockDim.x + threadIdx.x; i < N0 + N1 + N2;
         i += gridDim.x * blockDim.x) {
        const float* src; unsigned short* dst; int j;
        if (i < N0)           { src = x;  dst = xb;  j = i; }
        else if (i < N0 + N1) { src = wq; dst = wqb; j = i - N0; }
        else                  { src = wo; dst = wob; j = i - N0 - N1; }
        const float4 a = ((const float4*)src)[2*j];
        const float4 b = ((const float4*)src)[2*j + 1];
        union { unsigned short s[8]; uint4 u; } p;
        p.s[0]=f2bf(a.x); p.s[1]=f2bf(a.y); p.s[2]=f2bf(a.z); p.s[3]=f2bf(a.w);
        p.s[4]=f2bf(b.x); p.s[5]=f2bf(b.y); p.s[6]=f2bf(b.z); p.s[7]=f2bf(b.w);
        ((uint4*)dst)[j] = p.u;
    }
}

// ---------------------------------------------------------------------------
// bf16 GEMM: C[M,N] = A[M,K] @ W[N,K]^T + bias.  128x128 tile, BK=32,
// 4 waves (2x2), 64x64/wave. Double-buffered global_load_lds prefetch;
// XOR-swizzled LDS; XCD-aware 1D grid (nwg%8==0, bijective).
// OUT_MODE: 0 = f32 output.  2 = QKV mode: bf16 output for cols<2048,
// cols>=2048 (the V third) written TRANSPOSED into vt[(b*16+h)*64+d][s];
// the 4 mi-chunks (same vt row, s+0/16/32/48) are buffered and emitted as
// ONE 128B-contiguous burst per lane (full cache lines, no write amp).
// ---------------------------------------------------------------------------
template<int OUT_MODE>
__global__ __launch_bounds__(256) void gemm_bf16_mfma(
    const unsigned short* __restrict__ A, const unsigned short* __restrict__ W,
    const float* __restrict__ bias, void* __restrict__ Cout,
    unsigned short* __restrict__ vt,
    int M, int N, int K, int nbx)
{
    __shared__ __align__(16) char lds[32768];   // A0 B0 A1 B1 (8KB each)
    unsigned short* base = (unsigned short*)lds;

    const int tid = threadIdx.x;
    const int w = tid >> 6, l = tid & 63;
    const int wr = w >> 1, wc = w & 1;
    const int fr = l & 15, fq = l >> 4;

    // XCD-aware decode: consecutive nid on one XCD share the A row-panel
    const int qx  = gridDim.x >> 3;
    const int nid = (blockIdx.x & 7) * qx + (blockIdx.x >> 3);
    const int bx  = nid % nbx, by = nid / nbx;
    const int row0 = by * 128, col0 = bx * 128;

    const int sr0 = (w*2 + 0)*16 + (l >> 2);
    const int sr1 = (w*2 + 1)*16 + (l >> 2);
    const int skz = (((l & 3) ^ ((l >> 3) & 3))) * 8;   // swizzled source col

    const unsigned short* Ab0 = A + (size_t)(row0 + sr0)*K + skz;
    const unsigned short* Ab1 = A + (size_t)(row0 + sr1)*K + skz;
    const unsigned short* Wb0 = W + (size_t)(col0 + sr0)*K + skz;
    const unsigned short* Wb1 = W + (size_t)(col0 + sr1)*K + skz;

    f32x4 acc[4][4];
#pragma unroll
    for (int mi = 0; mi < 4; ++mi)
#pragma unroll
        for (int ni = 0; ni < 4; ++ni)
#pragma unroll
            for (int r = 0; r < 4; ++r) acc[mi][ni][r] = 0.f;

    const int cfa = (fq ^ ((fr >> 1) & 3)) * 8;

    auto stage = [&](int k0, int buf) {
        unsigned short* Ad = base + buf*8192;
        unsigned short* Wd = Ad + 4096;
        gl16(Ab0 + k0, Ad + (w*2 + 0)*512);
        gl16(Ab1 + k0, Ad + (w*2 + 1)*512);
        gl16(Wb0 + k0, Wd + (w*2 + 0)*512);
        gl16(Wb1 + k0, Wd + (w*2 + 1)*512);
    };

    stage(0, 0);
    for (int k0 = 0; k0 < K; k0 += 32) {
        const int buf = (k0 >> 5) & 1;
        __syncthreads();                    // tile(k0) ready
        if (k0 + 32 < K) stage(k0 + 32, buf ^ 1);

        const unsigned short* Ac = base + buf*8192;
        const unsigned short* Wc = Ac + 4096;
        short8 af[4], bf[4];
#pragma unroll
        for (int mi = 0; mi < 4; ++mi)
            af[mi] = *(const short8*)(Ac + (wr*64 + mi*16 + fr)*32 + cfa);
#pragma unroll
        for (int ni = 0; ni < 4; ++ni)
            bf[ni] = *(const short8*)(Wc + (wc*64 + ni*16 + fr)*32 + cfa);
#pragma unroll
        for (int mi = 0; mi < 4; ++mi)
#pragma unroll
            for (int ni = 0; ni < 4; ++ni)
                acc[mi][ni] = __builtin_amdgcn_mfma_f32_16x16x32_bf16(
                    af[mi], bf[ni], acc[mi][ni], 0, 0, 0);
    }

    float bv[4];
#pragma unroll
    for (int ni = 0; ni < 4; ++ni) bv[ni] = bias[col0 + wc*64 + ni*16 + fr];
#pragma unroll
    for (int mi = 0; mi < 4; ++mi)
#pragma unroll
        for (int ni = 0; ni < 4; ++ni)
#pragma unroll
            for (int r = 0; r < 4; ++r) acc[mi][ni][r] += bv[ni];

    __syncthreads();                           // tiles dead; reuse LDS for repack
    float* rp = (float*)lds + w*1088;          // per-wave [16][68] f32
    const int orow = l >> 2, oc = (l & 3) * 16;
    const bool vmode = (OUT_MODE == 2) && (col0 >= 2048);
    const int hh = vmode ? ((col0 + wc*64 - 2048) >> 6) : 0;

    // vmode: all 4 mi-chunks land in ONE vt row at s-offsets +0/16/32/48
    uint4 vbuf[4][2];
    unsigned short* vdst = nullptr;
    if (vmode) {
        const int srow0 = row0 + wr*64;        // mi adds +16, never crosses 2048
        const int bb = srow0 >> 11, ss = srow0 & 2047;
        vdst = vt + ((size_t)((bb*16 + hh)*64 + l))*SEQ + ss;
    }

#pragma unroll
    for (int mi = 0; mi < 4; ++mi) {
#pragma unroll
        for (int ni = 0; ni < 4; ++ni)
#pragma unroll
            for (int r = 0; r < 4; ++r)
                rp[(fq*4 + r)*68 + ni*16 + fr] = acc[mi][ni][r];
        // wave-lockstep: compiler orders LDS write->read within the wave
        if (vmode) {
            // TRANSPOSED V: lane l = head-dim column d; 16 s-values -> buffer
            float cv[16];
#pragma unroll
            for (int j = 0; j < 16; ++j) cv[j] = rp[j*68 + l];
            union { unsigned short s[16]; uint4 u[2]; } pk;
#pragma unroll
            for (int j = 0; j < 16; ++j) pk.s[j] = f2bf(cv[j]);
            vbuf[mi][0] = pk.u[0];
            vbuf[mi][1] = pk.u[1];
        } else {
            float vrow[16];
#pragma unroll
            for (int j = 0; j < 4; ++j)
                *(f32x4*)&vrow[j*4] = *(const f32x4*)&rp[orow*68 + oc + j*4];
            const size_t grow = (size_t)(row0 + wr*64 + mi*16 + orow);
            const int    gcol = col0 + wc*64 + oc;
            if (OUT_MODE == 2) {
                union { unsigned short s[16]; uint4 u[2]; } pk;
#pragma unroll
                for (int j = 0; j < 16; ++j) pk.s[j] = f2bf(vrow[j]);
                uint4* dst = (uint4*)((unsigned short*)Cout + grow*N + gcol);
                dst[0] = pk.u[0]; dst[1] = pk.u[1];
            } else {
                float* dst = (float*)Cout + grow*N + gcol;
#pragma unroll
                for (int j = 0; j < 4; ++j)
                    *(f32x4*)(dst + j*4) = *(const f32x4*)&vrow[j*4];
            }
        }
    }
    if (vmode) {
        // one 128B-contiguous burst per lane (8 x b128)
#pragma unroll
        for (int mi = 0; mi < 4; ++mi) {
            *((uint4*)(vdst + mi*16) + 0) = vbuf[mi][0];
            *((uint4*)(vdst + mi*16) + 1) = vbuf[mi][1];
        }
    }
}

// ---------------------------------------------------------------------------
// MFMA flash attention. 4 waves / 256 threads, QBLK=128 (32 q-rows/wave),
// KVBLK=32, pool 34816 B -> 4 blocks/CU (grid 1024) = 16 waves/CU.
// STATIC softmax: S^T = mfma(K, Q*SC2); P = v_exp_f32(S); l = mfma(ones,P);
// O^T = mfma(V^T, P^T).  (round-20 version, at this structure's ceiling)
// ---------------------------------------------------------------------------
__global__ __launch_bounds__(256) void attn_mfma(
    const unsigned short* __restrict__ qkvb,
    const unsigned short* __restrict__ vt,
    unsigned short* __restrict__ ctxb)
{
    __shared__ __align__(16) char pool[34816];
    unsigned short* hw = (unsigned short*)pool;

    const int tid = threadIdx.x, w = tid >> 6, l = tid & 63;
    const int fr = l & 15, fq = l >> 4;

    // XCD-aware decode (1024 blocks, 8 XCDs, bijective since 1024%8==0)
    const int bid = blockIdx.x;
    const int nid = (bid & 7) * 128 + (bid >> 3);
    const int b  = nid >> 8;
    const int h  = (nid >> 4) & 15;
    const int q0 = (nid & 15) * 128;
    const int wq = q0 + w*32;                      // 32 q-rows per wave

    const unsigned short* qb = qkvb + (size_t)b*SEQ*3072 + h*64;
    const unsigned short* kb = qb + 1024;
    const unsigned short* vb = vt + (size_t)((b*16 + h)*64)*SEQ;

    // Q fragments, scaled by SC2 once (bf16 relative precision unchanged)
    auto scale8 = [](short8 v) -> short8 {
        union { short8 s; unsigned u[4]; } in, out;
        in.s = v;
#pragma unroll
        for (int i = 0; i < 4; ++i) {
            const float lo = __uint_as_float(in.u[i] << 16) * SC2;
            const float hi = __uint_as_float(in.u[i] & 0xffff0000u) * SC2;
            unsigned r;
            asm("v_cvt_pk_bf16_f32 %0, %1, %2" : "=v"(r) : "v"(lo), "v"(hi));
            out.u[i] = r;
        }
        return out.s;
    };
    short8 qf[2][2];
#pragma unroll
    for (int mf = 0; mf < 2; ++mf)
#pragma unroll
        for (int kk = 0; kk < 2; ++kk)
            qf[mf][kk] = scale8(*(const short8*)(qb + (size_t)(wq + mf*16 + fr)*3072
                                                 + kk*32 + fq*8));

    short8 ones;
#pragma unroll
    for (int i = 0; i < 8; ++i) ones[i] = (short)0x3F80;   // bf16 1.0

    f32x4 z4;
#pragma unroll
    for (int r = 0; r < 4; ++r) z4[r] = 0.f;

    f32x4 o[2][4];     // o[mf][df][r]: q=mf*16+fr, d=df*16+fq*4+r
    f32x4 ol[2];       // l accumulators
#pragma unroll
    for (int mf = 0; mf < 2; ++mf) {
#pragma unroll
        for (int df = 0; df < 4; ++df)
#pragma unroll
            for (int r = 0; r < 4; ++r) o[mf][df][r] = 0.f;
#pragma unroll
        for (int r = 0; r < 4; ++r) ol[mf][r] = 0.f;
    }

    // K staging: wave w covers rows w*8..w*8+7; lane row w*8+(l>>3), chunk l&7
    const int srK  = w*8 + (l >> 3);
    const int sczK = ((l & 7) ^ (l >> 3)) * 8;
    // V staging: wave w covers rows w*16..+15; lane row w*16+(l>>2), chunk l&3
    const int srV  = w*16 + (l >> 2);
    const int sczV = ((l & 3) ^ ((w*8 + (l >> 3)) & 3)) * 8;   // (row>>1)&3 swizzle

    unsigned short* Pw = hw + 8192 + w*1280;       // [32][40]

    const int cK0 = (fq ^ (fr & 7)) * 8;           // K frag chunk (d 0..31)
    const int cK1 = cK0 ^ 32;                      // d 32..63
    const int cV  = (fq ^ ((fr >> 1) & 3)) * 8;    // V frag chunk

    auto stage = [&](int kv0, int buf) {
        gl16(kb + (size_t)(kv0 + srK)*3072 + sczK, hw + buf*2048 + w*512);
        gl16(vb + (size_t)srV*SEQ + kv0 + sczV,    hw + 4096 + buf*2048 + w*512);
    };

    stage(0, 0);
    for (int kv0 = 0; kv0 < SEQ; kv0 += 32) {
        const int buf = (kv0 >> 5) & 1;
        __syncthreads();                 // tile(kv0) DMA done; buf^1 free
        if (kv0 + 32 < SEQ) stage(kv0 + 32, buf ^ 1);

        const unsigned short* Kc = hw + buf*2048;
        const unsigned short* Vc = hw + 4096 + buf*2048;

        // V fragments EARLY (latency overlaps S + exp)
        short8 vf[4];
#pragma unroll
        for (int df = 0; df < 4; ++df)
            vf[df] = *(const short8*)(Vc + (df*16 + fr)*32 + cV);

        // ---- S^T = K (Q*SC2)^T ----
        f32x4 s[2][2];
#pragma unroll
        for (int nf = 0; nf < 2; ++nf) {
            const short8 k0f = *(const short8*)(Kc + (nf*16 + fr)*64 + cK0);
            const short8 k1f = *(const short8*)(Kc + (nf*16 + fr)*64 + cK1);
#pragma unroll
            for (int mf = 0; mf < 2; ++mf) {
                s[mf][nf] = __builtin_amdgcn_mfma_f32_16x16x32_bf16(k0f, qf[mf][0], z4, 0,0,0);
                s[mf][nf] = __builtin_amdgcn_mfma_f32_16x16x32_bf16(k1f, qf[mf][1], s[mf][nf], 0,0,0);
            }
        }

        // ---- P = exp2(s), pack bf16, uint2 store into P[32][40] ----
#pragma unroll
        for (int mf = 0; mf < 2; ++mf)
#pragma unroll
            for (int nf = 0; nf < 2; ++nf) {
                const float p0 = fexp2(s[mf][nf][0]);
                const float p1 = fexp2(s[mf][nf][1]);
                const float p2 = fexp2(s[mf][nf][2]);
                const float p3 = fexp2(s[mf][nf][3]);
                unsigned u0, u1;
                asm("v_cvt_pk_bf16_f32 %0, %1, %2" : "=v"(u0) : "v"(p0), "v"(p1));
                asm("v_cvt_pk_bf16_f32 %0, %1, %2" : "=v"(u1) : "v"(p2), "v"(p3));
                uint2 pw; pw.x = u0; pw.y = u1;
                *(uint2*)(Pw + (mf*16 + fr)*40 + nf*16 + fq*4) = pw;
            }

        // ---- O^T += V^T P^T ; l += ones . P^T  (kv=32: one mfma each) ----
        short8 pa[2];
#pragma unroll
        for (int mf = 0; mf < 2; ++mf)
            pa[mf] = *(const short8*)(Pw + (mf*16 + fr)*40 + fq*8);
#pragma unroll
        for (int mf = 0; mf < 2; ++mf)
            ol[mf] = __builtin_amdgcn_mfma_f32_16x16x32_bf16(ones, pa[mf], ol[mf], 0,0,0);
#pragma unroll
        for (int df = 0; df < 4; ++df)
#pragma unroll
            for (int mf = 0; mf < 2; ++mf)
                o[mf][df] = __builtin_amdgcn_mfma_f32_16x16x32_bf16(
                    vf[df], pa[mf], o[mf][df], 0,0,0);
    }

    // ---- normalize + coalesced store via per-wave LDS repack ----
    __syncthreads();
    float* rp = (float*)(pool + w*8704);   // [32][68] f32, wave-private
    const float inv0 = 1.f / ol[0][0], inv1 = 1.f / ol[1][0];
#pragma unroll
    for (int df = 0; df < 4; ++df) {
        f32x4 v0 = o[0][df] * inv0;
        f32x4 v1 = o[1][df] * inv1;
        *(f32x4*)&rp[(fr)*68      + df*16 + fq*4] = v0;
        *(f32x4*)&rp[(16 + fr)*68 + df*16 + fq*4] = v1;
    }
    const int orow = l >> 1, oc = (l & 1)*32;
    float vr[32];
#pragma unroll
    for (int j = 0; j < 8; ++j)
        *(f32x4*)&vr[j*4] = *(const f32x4*)&rp[orow*68 + oc + j*4];
    union { unsigned short s[32]; uint4 u[4]; } pk;
#pragma unroll
    for (int j = 0; j < 32; ++j) pk.s[j] = f2bf(vr[j]);
    unsigned short* dst = ctxb + (size_t)(b*SEQ + q0 + w*32 + orow)*DIMC + h*64 + oc;
#pragma unroll
    for (int j = 0; j < 4; ++j) *((uint4*)dst + j) = pk.u[j];
}

} // namespace

extern "C" void kernel_launch(void* const* d_in, const int* in_sizes, int n_in,
                              void* d_out, int out_size, void* d_ws, size_t ws_size,
                              hipStream_t stream)
{
    const float* x     = (const float*)d_in[0];
    const float* qkv_w = (const float*)d_in[1];
    const float* qkv_b = (const float*)d_in[2];
    const float* out_w = (const float*)d_in[3];
    const float* out_b = (const float*)d_in[4];

    // workspace carve (bf16 buffers), ~109 MB total
    unsigned short* xb   = (unsigned short*)d_ws;              // [8192][1024]
    unsigned short* wqb  = xb   + (size_t)8192*1024;           // [3072][1024]
    unsigned short* wob  = wqb  + (size_t)3072*1024;           // [1024][1024]
    unsigned short* qkvb = wob  + (size_t)1024*1024;           // [8192][3072] (V third unused)
    unsigned short* vtw  = qkvb + (size_t)8192*3072;           // [4096][2048]
    unsigned short* ctxb = vtw  + (size_t)4096*2048;           // [8192][1024]

    // 1) fused fp32 -> bf16 conversions (one launch)
    cvt3_f32_bf16<<<2048, 256, 0, stream>>>(x, qkv_w, out_w, xb, wqb, wob);

    // 2) QKV projection (bf16 out; V third written transposed into vtw,
    //    now with coalesced 128B-per-lane bursts)
    gemm_bf16_mfma<2><<<dim3(1536), 256, 0, stream>>>(
        xb, wqb, qkv_b, (void*)qkvb, vtw, 8192, 3072, 1024, 24);

    // 3) flash attention (QBLK=128, KVBLK=32, 4 blocks/CU) -> ctx bf16
    attn_mfma<<<dim3(1024), 256, 0, stream>>>(qkvb, vtw, ctxb);

    // 4) output projection (f32 out): [8192,1024]x[1024,1024]^T + bias
    gemm_bf16_mfma<0><<<dim3(512), 256, 0, stream>>>(
        ctxb, wob, out_b, d_out, nullptr, 8192, 1024, 1024, 8);
}